// Round 6
// baseline (39.052 us; speedup 1.0000x reference)
//
#include <hip/hip_runtime.h>

// YOLO v1 loss, forward only. preds/labels: [16384, 7, 7, 30] f32 -> scalar f32.
//
// Structure: 1-wave blocks (64 lanes), 2 blocks/CU (grid 512). Tile = 128
// cells = 15360 B/array = 15 chunks of (64 lanes x 16 B) per array, staged by
// async global_load_lds width 16 (the HW-verified width). Depth-1 counted
// pipeline over 2 LDS buffers: issue tile t+1's 30 chunks, then
// s_waitcnt vmcnt(30) -> tile t ready while t+1 stays in flight. No
// __syncthreads anywhere (single wave); never drains to vmcnt(0) mid-stream.
#define NCELLS (16384 * 7 * 7)       // 802816
#define TILE 128                     // cells per tile (2 per lane)
#define TFLOATS (TILE * 30)          // 3840 floats = 15360 B per array
#define NTILES (NCELLS / TILE)       // 6272 exactly
#define GRID 512                     // 2 one-wave blocks per CU
#define CHUNKS 15                    // 15360 B / (64 lanes * 16 B)
// vmem instrs per tile per wave = 2*CHUNKS = 30; max outstanding 60 (<63)

__device__ __forceinline__ void gload16(const float* g, float* l) {
    // async global->LDS DMA, 16 B per lane; LDS dest = uniform base + lane*16.
    __builtin_amdgcn_global_load_lds(
        (const __attribute__((address_space(1))) void*)g,
        (__attribute__((address_space(3))) void*)l, 16, 0, 0);
}

__device__ __forceinline__ void stage_tile(const float* __restrict__ preds,
                                           const float* __restrict__ labels,
                                           float* sp, float* sl,
                                           int tile, int lane) {
    size_t base = (size_t)tile * TFLOATS;
    #pragma unroll
    for (int c = 0; c < CHUNKS; ++c)
        gload16(preds + base + c * 256 + lane * 4, sp + c * 256);
    #pragma unroll
    for (int c = 0; c < CHUNKS; ++c)
        gload16(labels + base + c * 256 + lane * 4, sl + c * 256);
}

__device__ __forceinline__ float cell_loss(const float* p, const float* l) {
    float g_l = l[0] - l[2] * 0.5f, g_r = l[0] + l[2] * 0.5f;
    float g_t = l[1] - l[3] * 0.5f, g_b = l[1] + l[3] * 0.5f;
    float area_g = l[2] * l[3];

    float a_l = p[0] - p[2] * 0.5f, a_r = p[0] + p[2] * 0.5f;
    float a_t = p[1] - p[3] * 0.5f, a_b = p[1] + p[3] * 0.5f;
    float iw1 = fmaxf(fminf(a_r, g_r) - fmaxf(a_l, g_l), 0.0f);
    float ih1 = fmaxf(fminf(a_b, g_b) - fmaxf(a_t, g_t), 0.0f);
    float inter1 = iw1 * ih1;
    float iou1 = inter1 / (p[2] * p[3] + area_g - inter1 + 1e-10f);

    float b_l = p[5] - p[7] * 0.5f, b_r = p[5] + p[7] * 0.5f;
    float b_t = p[6] - p[8] * 0.5f, b_b = p[6] + p[8] * 0.5f;
    float iw2 = fmaxf(fminf(b_r, g_r) - fmaxf(b_l, g_l), 0.0f);
    float ih2 = fmaxf(fminf(b_b, g_b) - fmaxf(b_t, g_t), 0.0f);
    float inter2 = iw2 * ih2;
    float iou2 = inter2 / (p[7] * p[8] + area_g - inter2 + 1e-10f);

    bool r1 = iou1 > iou2;
    float rb0 = r1 ? p[0] : p[5];
    float rb1 = r1 ? p[1] : p[6];
    float rb2 = r1 ? p[2] : p[7];
    float rb3 = r1 ? p[3] : p[8];
    float rconf = r1 ? p[4] : p[9];
    float oconf = r1 ? p[9] : p[4];
    float riou = fmaxf(iou1, iou2);

    float dx = rb0 - l[0], dy = rb1 - l[1];
    float lxy = dx * dx + dy * dy;

    float spw = sqrtf(fmaxf(rb2, 1e-8f)), sgw = sqrtf(fmaxf(l[2], 1e-8f));
    float sph = sqrtf(fmaxf(rb3, 1e-8f)), sgh = sqrtf(fmaxf(l[3], 1e-8f));
    float dw = spw - sgw, dh = sph - sgh;
    float lwh = dw * dw + dh * dh;

    float dob = rconf - riou;

    float cls = 0.0f;
    #pragma unroll
    for (int c = 10; c < 30; ++c) {
        float d = p[c] - l[c];
        cls += d * d;
    }

    float obj = l[4];
    return obj * (5.0f * (lxy + lwh) + dob * dob + 0.5f * oconf * oconf + cls)
         + 0.5f * (1.0f - obj) * (p[4] * p[4] + p[9] * p[9]);
}

__global__ __launch_bounds__(64) void yolo_partial(
        const float* __restrict__ preds, const float* __restrict__ labels,
        float* __restrict__ partials) {
    __shared__ float S[2][2][TFLOATS];   // 2 bufs x (preds, labels) = 61440 B

    int lane = threadIdx.x;              // 0..63
    int t0 = blockIdx.x;                 // < NTILES always (GRID << NTILES)
    float acc = 0.0f;

    stage_tile(preds, labels, S[0][0], S[0][1], t0, lane);

    int buf = 0;
    for (int t = t0; t < NTILES; t += GRID) {
        int tn = t + GRID;
        if (tn < NTILES) {
            stage_tile(preds, labels, S[buf ^ 1][0], S[buf ^ 1][1], tn, lane);
            // 60 outstanding; wait until <=30 -> tile t's 30 retired (in-order),
            // tile t+1's 30 remain in flight across the compute below.
            asm volatile("s_waitcnt vmcnt(30)" ::: "memory");
        } else {
            asm volatile("s_waitcnt vmcnt(0)" ::: "memory");
        }
        __builtin_amdgcn_sched_barrier(0);   // pin: no LDS read hoists above wait

        // this lane's two cells; one live 60-float set at a time (no spills:
        // scratch ops would count in vmcnt and break the counted waits).
        #pragma unroll
        for (int h = 0; h < 2; ++h) {
            int cell = h * 64 + lane;
            const float2* cp = (const float2*)(S[buf][0] + cell * 30);
            const float2* cl = (const float2*)(S[buf][1] + cell * 30);
            float p[30], l[30];
            #pragma unroll
            for (int i = 0; i < 15; ++i) {
                float2 v = cp[i]; p[2 * i] = v.x; p[2 * i + 1] = v.y;
            }
            #pragma unroll
            for (int i = 0; i < 15; ++i) {
                float2 v = cl[i]; l[2 * i] = v.x; l[2 * i + 1] = v.y;
            }
            acc += cell_loss(p, l);
        }

        buf ^= 1;
    }

    // single-wave reduction; deterministic order
    #pragma unroll
    for (int off = 32; off > 0; off >>= 1) acc += __shfl_down(acc, off);
    if (lane == 0) partials[blockIdx.x] = acc;
}

__global__ __launch_bounds__(256) void yolo_final(
        const float* __restrict__ partials, float* __restrict__ out) {
    float acc = 0.0f;
    for (int i = threadIdx.x; i < GRID; i += 256) acc += partials[i];
    #pragma unroll
    for (int off = 32; off > 0; off >>= 1) acc += __shfl_down(acc, off);
    __shared__ float s[4];
    int lane = threadIdx.x & 63, wid = threadIdx.x >> 6;
    if (lane == 0) s[wid] = acc;
    __syncthreads();
    if (threadIdx.x == 0)
        out[0] = (s[0] + s[1] + s[2] + s[3]) * (1.0f / 16384.0f);
}

extern "C" void kernel_launch(void* const* d_in, const int* in_sizes, int n_in,
                              void* d_out, int out_size, void* d_ws, size_t ws_size,
                              hipStream_t stream) {
    const float* preds  = (const float*)d_in[0];
    const float* labels = (const float*)d_in[1];
    float* out = (float*)d_out;
    float* partials = (float*)d_ws;   // GRID * 4 B = 2 KB

    yolo_partial<<<GRID, 64, 0, stream>>>(preds, labels, partials);
    yolo_final<<<1, 256, 0, stream>>>(partials, out);
}

// Round 7
// 35.155 us; speedup vs baseline: 1.1108x; 1.1108x over previous
//
#include <hip/hip_runtime.h>

// YOLO v1 loss, forward only. preds/labels: [16384, 7, 7, 30] f32 -> scalar f32.
//
// R7: R3's proven DMA-staged structure, tile halved to 128 cells so LDS/block
// = 61440 B -> 2 blocks/CU (grid 512), 8 DMA-fed waves/CU. The per-tile
// vmcnt(0)+barrier drain of one block overlaps with the other block's DMA
// stream on the same CU. Double-buffered global_load_lds width 16.
#define NCELLS (16384 * 7 * 7)          // 802816
#define THREADS 256
#define TILE_CELLS 128
#define FLOATS_PER_TILE (TILE_CELLS * 30)   // 3840 floats = 15360 B per array
#define NTILES (NCELLS / TILE_CELLS)        // 6272 exactly
#define GRID 512                            // 2 blocks per CU

__device__ __forceinline__ void gload16(const float* g, float* l) {
    // async global->LDS DMA, 16 B per lane; LDS dest = uniform base + lane*16.
    __builtin_amdgcn_global_load_lds(
        (const __attribute__((address_space(1))) void*)g,
        (__attribute__((address_space(3))) void*)l, 16, 0, 0);
}

// One tile = 30 chunks of 256 floats (64 lanes x 16 B): preds c0..14 -> sp,
// labels c0..14 -> sl. Wave w takes chunks g = w, w+4, ... (8 or 7 each).
__device__ __forceinline__ void stage_tile(const float* __restrict__ preds,
                                           const float* __restrict__ labels,
                                           float* sp, float* sl,
                                           int tile, int wid, int lane) {
    size_t base = (size_t)tile * FLOATS_PER_TILE;
    #pragma unroll
    for (int g = wid; g < 30; g += 4) {
        if (g < 15) {
            gload16(preds + base + (size_t)g * 256 + lane * 4, sp + g * 256);
        } else {
            int c = g - 15;
            gload16(labels + base + (size_t)c * 256 + lane * 4, sl + c * 256);
        }
    }
}

__device__ __forceinline__ float cell_loss(const float* p, const float* l) {
    float g_l = l[0] - l[2] * 0.5f, g_r = l[0] + l[2] * 0.5f;
    float g_t = l[1] - l[3] * 0.5f, g_b = l[1] + l[3] * 0.5f;
    float area_g = l[2] * l[3];

    float a_l = p[0] - p[2] * 0.5f, a_r = p[0] + p[2] * 0.5f;
    float a_t = p[1] - p[3] * 0.5f, a_b = p[1] + p[3] * 0.5f;
    float iw1 = fmaxf(fminf(a_r, g_r) - fmaxf(a_l, g_l), 0.0f);
    float ih1 = fmaxf(fminf(a_b, g_b) - fmaxf(a_t, g_t), 0.0f);
    float inter1 = iw1 * ih1;
    float iou1 = inter1 / (p[2] * p[3] + area_g - inter1 + 1e-10f);

    float b_l = p[5] - p[7] * 0.5f, b_r = p[5] + p[7] * 0.5f;
    float b_t = p[6] - p[8] * 0.5f, b_b = p[6] + p[8] * 0.5f;
    float iw2 = fmaxf(fminf(b_r, g_r) - fmaxf(b_l, g_l), 0.0f);
    float ih2 = fmaxf(fminf(b_b, g_b) - fmaxf(b_t, g_t), 0.0f);
    float inter2 = iw2 * ih2;
    float iou2 = inter2 / (p[7] * p[8] + area_g - inter2 + 1e-10f);

    bool r1 = iou1 > iou2;
    float rb0 = r1 ? p[0] : p[5];
    float rb1 = r1 ? p[1] : p[6];
    float rb2 = r1 ? p[2] : p[7];
    float rb3 = r1 ? p[3] : p[8];
    float rconf = r1 ? p[4] : p[9];
    float oconf = r1 ? p[9] : p[4];
    float riou = fmaxf(iou1, iou2);

    float dx = rb0 - l[0], dy = rb1 - l[1];
    float lxy = dx * dx + dy * dy;

    float spw = sqrtf(fmaxf(rb2, 1e-8f)), sgw = sqrtf(fmaxf(l[2], 1e-8f));
    float sph = sqrtf(fmaxf(rb3, 1e-8f)), sgh = sqrtf(fmaxf(l[3], 1e-8f));
    float dw = spw - sgw, dh = sph - sgh;
    float lwh = dw * dw + dh * dh;

    float dob = rconf - riou;

    float cls = 0.0f;
    #pragma unroll
    for (int c = 10; c < 30; ++c) {
        float d = p[c] - l[c];
        cls += d * d;
    }

    float obj = l[4];
    return obj * (5.0f * (lxy + lwh) + dob * dob + 0.5f * oconf * oconf + cls)
         + 0.5f * (1.0f - obj) * (p[4] * p[4] + p[9] * p[9]);
}

__device__ __forceinline__ float block_reduce(float acc) {
    #pragma unroll
    for (int off = 32; off > 0; off >>= 1) acc += __shfl_down(acc, off);
    __shared__ float s[THREADS / 64];
    int lane = threadIdx.x & 63, wid = threadIdx.x >> 6;
    if (lane == 0) s[wid] = acc;
    __syncthreads();
    float r = 0.0f;
    if (threadIdx.x == 0) {
        #pragma unroll
        for (int w = 0; w < THREADS / 64; ++w) r += s[w];
    }
    return r;
}

__global__ __launch_bounds__(THREADS, 2) void yolo_partial(
        const float* __restrict__ preds, const float* __restrict__ labels,
        float* __restrict__ partials) {
    __shared__ float sp[2][FLOATS_PER_TILE];   // 2 x 15360 B
    __shared__ float sl[2][FLOATS_PER_TILE];   // 2 x 15360 B  (total 61440 B)

    int lane = threadIdx.x & 63, wid = threadIdx.x >> 6;
    float acc = 0.0f;

    int tile = blockIdx.x;
    int buf = 0;
    if (tile < NTILES) stage_tile(preds, labels, sp[0], sl[0], tile, wid, lane);

    for (; tile < NTILES; tile += GRID, buf ^= 1) {
        // wait this wave's outstanding DMAs, then block-wide: buffer valid.
        asm volatile("s_waitcnt vmcnt(0)" ::: "memory");
        __syncthreads();
        // prefetch next tile into the other buffer (in flight during compute)
        int next = tile + GRID;
        if (next < NTILES)
            stage_tile(preds, labels, sp[buf ^ 1], sl[buf ^ 1], next, wid, lane);

        // one cell per thread (128 cells, threads 128..255 idle on gather? no:
        // TILE_CELLS=128 < THREADS=256 -> only low 128 threads gather/compute)
        if (threadIdx.x < TILE_CELLS) {
            const float2* cp = (const float2*)(sp[buf] + threadIdx.x * 30);
            const float2* cl = (const float2*)(sl[buf] + threadIdx.x * 30);
            float p[30], l[30];
            #pragma unroll
            for (int i = 0; i < 15; ++i) {
                float2 v = cp[i]; p[2 * i] = v.x; p[2 * i + 1] = v.y;
            }
            #pragma unroll
            for (int i = 0; i < 15; ++i) {
                float2 v = cl[i]; l[2 * i] = v.x; l[2 * i + 1] = v.y;
            }
            acc += cell_loss(p, l);
        }
    }

    float r = block_reduce(acc);
    if (threadIdx.x == 0) partials[blockIdx.x] = r;
}

__global__ __launch_bounds__(256) void yolo_final(
        const float* __restrict__ partials, float* __restrict__ out) {
    float acc = 0.0f;
    for (int i = threadIdx.x; i < GRID; i += 256) acc += partials[i];
    #pragma unroll
    for (int off = 32; off > 0; off >>= 1) acc += __shfl_down(acc, off);
    __shared__ float s[4];
    int lane = threadIdx.x & 63, wid = threadIdx.x >> 6;
    if (lane == 0) s[wid] = acc;
    __syncthreads();
    if (threadIdx.x == 0)
        out[0] = (s[0] + s[1] + s[2] + s[3]) * (1.0f / 16384.0f);
}

extern "C" void kernel_launch(void* const* d_in, const int* in_sizes, int n_in,
                              void* d_out, int out_size, void* d_ws, size_t ws_size,
                              hipStream_t stream) {
    const float* preds  = (const float*)d_in[0];
    const float* labels = (const float*)d_in[1];
    float* out = (float*)d_out;
    float* partials = (float*)d_ws;   // GRID * 4 B = 2 KB

    yolo_partial<<<GRID, THREADS, 0, stream>>>(preds, labels, partials);
    yolo_final<<<1, 256, 0, stream>>>(partials, out);
}